// Round 6
// baseline (187.853 us; speedup 1.0000x reference)
//
#include <hip/hip_runtime.h>

typedef unsigned int u32;
typedef unsigned short u16;
typedef unsigned char u8;
typedef __attribute__((ext_vector_type(8))) __bf16 bf16x8;
typedef __attribute__((ext_vector_type(4))) float f32x4;
typedef __attribute__((ext_vector_type(4))) int i32x4;

#define NB 16384
#define NM 4096
#define ND 512
#define NOUT 128
#define L2E 1.44269504088896340736f

// ws layout: x_ws fp8 [rb(256)][kg64(64)][row(64)][8B]   (8 MB)
//            s_ws fp8 [mb(32)][kg64(64)][m(128)][8B]     (2 MB, pre-scaled by -2*gamma*log2e)
//            hw_ws bf16 [slab=(mb*16+kg)][o(128)][8]     (1 MB)
// x2g[16384] = gamma*log2e*||x||^2 ; s2g[4096] = gamma*log2e*||s||^2  (fp32-exact)

#define WAITLG(N) do { asm volatile("s_waitcnt vmcnt(" #N ") lgkmcnt(0)" ::: "memory"); \
                       __builtin_amdgcn_sched_barrier(0); } while (0)
#define LGKM0() do { asm volatile("s_waitcnt lgkmcnt(0)" ::: "memory"); \
                     __builtin_amdgcn_sched_barrier(0); } while (0)
#define SB0() __builtin_amdgcn_sched_barrier(0)

// ---------- helpers ----------
__device__ __forceinline__ u16 f2bf(float f) {
  u32 u = __float_as_uint(f);
  u += 0x7FFFu + ((u >> 16) & 1u);   // RNE
  return (u16)(u >> 16);
}

// manual fp32 -> e4m3fn (RNE, flush |v|<2^-6 to 0; |v| <= ~15 here so no sat needed)
__device__ __forceinline__ u8 f2fp8(float f) {
  u32 u = __float_as_uint(f);
  u32 s = (u >> 24) & 0x80u;
  u32 au = u & 0x7FFFFFFFu;
  if (au < 0x3C800000u) return (u8)s;          // below min normal -> 0
  au += 0x000FFFFFu + ((au >> 20) & 1u);       // RNE to 3 mantissa bits
  u32 e = (au >> 23) - 120u;                   // rebias 127 -> 7
  u32 m = (au >> 20) & 7u;
  return (u8)(s | (e << 3) | m);
}

__device__ __forceinline__ void stage16(const void* g, void* l) {
  __builtin_amdgcn_global_load_lds((__attribute__((address_space(1))) void*)g,
                                   (__attribute__((address_space(3))) void*)l,
                                   16, 0, 0);
}

// compiler-invisible b128 global load: no forced compiler vmcnt before the
// consumer; my counted waits cover it (HW vmcnt counts asm loads too)
__device__ __forceinline__ bf16x8 ldg_b128(const void* p) {
  i32x4 r;
  asm volatile("global_load_dwordx4 %0, %1, off" : "=&v"(r) : "v"(p) : "memory");
  return __builtin_bit_cast(bf16x8, r);
}

__device__ __forceinline__ uint4 pack8bf(float4 v0, float4 v1) {
  uint4 pk;
  pk.x = (u32)f2bf(v0.x) | ((u32)f2bf(v0.y) << 16);
  pk.y = (u32)f2bf(v0.z) | ((u32)f2bf(v0.w) << 16);
  pk.z = (u32)f2bf(v1.x) | ((u32)f2bf(v1.y) << 16);
  pk.w = (u32)f2bf(v1.z) | ((u32)f2bf(v1.w) << 16);
  return pk;
}

__device__ __forceinline__ uint2 pack8f8(float4 v0, float4 v1) {
  uint2 pk;
  pk.x = (u32)f2fp8(v0.x) | ((u32)f2fp8(v0.y) << 8) |
         ((u32)f2fp8(v0.z) << 16) | ((u32)f2fp8(v0.w) << 24);
  pk.y = (u32)f2fp8(v1.x) | ((u32)f2fp8(v1.y) << 8) |
         ((u32)f2fp8(v1.z) << 16) | ((u32)f2fp8(v1.w) << 24);
  return pk;
}

// ---------- merged prep ----------
// blocks [0,512): x tiles (fp8)   [512,640): support tiles (fp8, scaled)
// [640,672): head_w (bf16)        [672,736): zero d_out (64 blocks x 128 KB)
__global__ __launch_bounds__(256) void prep_all(const float* __restrict__ x,
                                                const float* __restrict__ s,
                                                const float* __restrict__ hw,
                                                const float* __restrict__ gamma_p,
                                                u8*  __restrict__ x_ws,
                                                u8*  __restrict__ s_ws,
                                                u16* __restrict__ hw_ws,
                                                float* __restrict__ x2g,
                                                float* __restrict__ s2g,
                                                float* __restrict__ out) {
  __shared__ uint2 t8[2048];       // 16 KB (x/s transpose, XOR-swizzled)
  __shared__ uint4 t16[2048];      // 32 KB (hw transpose)
  const int tid = threadIdx.x, bid = blockIdx.x;
  const int lane = tid & 63, w = tid >> 6;

  if (bid < 640) {
    const bool isx = bid < 512;
    const int blk = isx ? bid : (bid - 512);
    const float* src_m = isx ? x : s;
    u8*    dst_ws = isx ? x_ws : s_ws;
    float* sq_out = isx ? x2g : s2g;
    const float gl   = gamma_p[0] * L2E;
    const float cmul = isx ? 1.0f : (-2.0f * gl);
    const int big  = isx ? (blk >> 1) : (blk >> 2);
    const int roff = isx ? ((blk & 1) * 32) : ((blk & 3) * 32);
    const int rows = isx ? 64 : 128;

    #pragma unroll
    for (int p = 0; p < 8; ++p) {
      const int row = p * 4 + w;                      // local row 0..31
      const float* src = src_m + (size_t)(blk * 32 + row) * ND + lane * 8;
      float4 v0 = *(const float4*)src;
      float4 v1 = *(const float4*)(src + 4);
      float ss = v0.x*v0.x + v0.y*v0.y + v0.z*v0.z + v0.w*v0.w
               + v1.x*v1.x + v1.y*v1.y + v1.z*v1.z + v1.w*v1.w;
      #pragma unroll
      for (int off = 32; off > 0; off >>= 1) ss += __shfl_down(ss, off);
      if (lane == 0) sq_out[blk * 32 + row] = gl * ss;
      v0.x *= cmul; v0.y *= cmul; v0.z *= cmul; v0.w *= cmul;
      v1.x *= cmul; v1.y *= cmul; v1.z *= cmul; v1.w *= cmul;
      t8[lane * 32 + ((row + lane) & 31)] = pack8f8(v0, v1);   // kg = lane
    }
    __syncthreads();
    #pragma unroll
    for (int p = 0; p < 8; ++p) {
      const int kg = p * 8 + (tid >> 5);
      const int row = tid & 31;
      uint2 pk = t8[kg * 32 + ((row + kg) & 31)];
      *(uint2*)&dst_ws[(((size_t)(big * 64 + kg)) * rows + roff + row) * 8] = pk;
    }
  } else if (bid < 672) {
    // ---- head_w: m-chunk of 128 (bf16) ----
    const int blk = bid - 640;
    #pragma unroll
    for (int p = 0; p < 8; ++p) {
      const int o = p * 16 + (tid >> 4);
      const int kg = tid & 15;
      const float* src = hw + (size_t)o * NM + blk * 128 + kg * 8;
      float4 v0 = *(const float4*)src;
      float4 v1 = *(const float4*)(src + 4);
      t16[o * 16 + ((kg + o) & 15)] = pack8bf(v0, v1);
    }
    __syncthreads();
    #pragma unroll
    for (int it = 0; it < 8; ++it) {
      const int kg = it * 2 + (tid >> 7);
      const int o = tid & 127;
      uint4 pk = t16[o * 16 + ((kg + o) & 15)];
      *(uint4*)&hw_ws[(((size_t)(blk * 16 + kg)) * 128 + o) * 8] = pk;
    }
  } else {
    // ---- zero d_out: 64 blocks x 128 KB ----
    float4* o4 = (float4*)out;
    const float4 z = {0.f, 0.f, 0.f, 0.f};
    size_t base = (size_t)(bid - 672) * 8192 + tid;
    #pragma unroll 8
    for (int i = 0; i < 32; ++i) o4[base + (size_t)i * 256] = z;
  }
}

// ---------- main fused kernel ----------
// R6: K=128 per barrier (32 slots of 36 MFMA instead of 64 of 18), X in REGISTERS
// (aX[16][2]; K-index within mt = 4s+i, mt-independent -> static), 256 thr / 4 waves /
// 32x64 wave tile / (256,2) as R5 (sane-allocator regime, R3's (512,4) clamp avoided).
// LDS 80KB dynamic: S ring 8 x 8K @0 (tile j -> buf j&7), Ks 16K @65536.
// Slot T = mt*4+s consumes tiles 2T,2T+1 (4 kc of K=32). Rolling kc pipeline:
//   [MFMA kc_i (8 fp8)] [4 ds_read b64 for kc_{i+1} (+a2 x2 b128 at i=0)] [lgkm0]
// kc0 regs were read at end of slot T-1 -> MFMA starts right after the barrier.
// Then: gemm2 (4 bf16, ks=s, Ks of mt-1); stage tiles 2T+6,7 (lead 3); b2(T+2) asm
// loads; WAITLG(N); s_barrier. N = exact FIFO count to drain stage(T-1)+b2(T+1)
// (never 0 in steady state): mt0 {10,4,8,8}; mt1-6 {12,8,8,8}; mt7 {12,4,0,0}.
// Hazards: RAW tile j (staged T-3, block-wide by barrier(T-1), first read mid-T);
// WAR ring reuse 8 tiles apart (>=3 barriers); Ks write(mt) after last gemm2
// read(mt-1) within the same barrier interval, ordered by epilogue lgkm0+barrier.
__global__ __launch_bounds__(256, 2)
void rbf_fused(const u8* __restrict__ x_ws, const u8* __restrict__ s_ws,
               const u16* __restrict__ hw_ws, const float* __restrict__ x2g,
               const float* __restrict__ s2g, const float* __restrict__ head_b,
               const float* __restrict__ scale_p, const float* __restrict__ shift_p,
               float* __restrict__ out)
{
  extern __shared__ __align__(16) char smem[];   // 80 KB dynamic

  const int tid  = threadIdx.x;
  const int w    = tid >> 6;
  const int lane = tid & 63;
  const int quad = lane >> 4;
  const int l16  = lane & 15;
  const int wr   = w & 1;    // row half (32 rows)
  const int wc   = w >> 1;   // m / out-col half (64)
  const int xcd  = blockIdx.x & 7;
  const int rb   = (blockIdx.x >> 3) * 2 + (xcd & 1);
  const int half = xcd >> 1;
  const int b0   = rb * 64;

  const float vscale = scale_p[0];
  const float vshift = shift_p[0];

  const u8* xsrc = x_ws + (size_t)rb * 32768;
  const u8* ssrc = s_ws + (size_t)(half * 8) * 65536;

  auto stage_tile = [&](int j) {         // tile j (K=64 chunk), 8 KB, buf j&7
    const u8* sp = ssrc + (size_t)(j >> 3) * 65536 + (j & 7) * 8192;
    char* dp = smem + (j & 7) * 8192;
    stage16(sp + tid * 16, dp + tid * 16);
    stage16(sp + 4096 + tid * 16, dp + 4096 + tid * 16);
  };

  // B-fragment read: 4 x ds_read_b64 from ring buf (buf, kcL static)
  auto rdB = [&](int buf, int kcL, long long* dst) {
    #pragma unroll
    for (int c = 0; c < 4; ++c)
      dst[c] = *(const long long*)(smem + buf * 8192 +
                ((kcL * 4 + quad) * 128 + wc * 64 + c * 16 + l16) * 8);
  };

  // ---- prologue: x2v(2 ev), X->regs(32 ev), stage tiles 0..5 (12 ev) ----
  f32x4 x2v[2];
  #pragma unroll
  for (int r = 0; r < 2; ++r)
    x2v[r] = *(const f32x4*)&x2g[b0 + wr * 32 + r * 16 + quad * 4];
  SB0();
  long long aX[16][2];
  #pragma unroll
  for (int kc = 0; kc < 16; ++kc)
    #pragma unroll
    for (int r = 0; r < 2; ++r)
      aX[kc][r] = *(const long long*)(xsrc + ((kc * 4 + quad) * 64 + wr * 32 + r * 16 + l16) * 8);
  SB0();
  #pragma unroll
  for (int j = 0; j < 6; ++j) stage_tile(j);
  asm volatile("s_waitcnt vmcnt(6)" ::: "memory");   // drain x2v,X,tiles0-2; leave 3,4,5
  SB0();
  __builtin_amdgcn_s_barrier();
  SB0();

  long long bF0[4], bF1[4];
  rdB(0, 0, bF0);                       // kc0 of slot 0
  LGKM0();

  const f32x4 zf = {0.f, 0.f, 0.f, 0.f};
  f32x4 acc_xs[2][4];
  f32x4 acc_out[2][4];
  #pragma unroll
  for (int r = 0; r < 2; ++r)
    #pragma unroll
    for (int c = 0; c < 4; ++c) { acc_xs[r][c] = zf; acc_out[r][c] = zf; }

  bf16x8 b2[2][4];                      // set s&1: consumed at slot T, re-issued for T+2

  #pragma unroll 1
  for (int mt = 0; mt < 8; ++mt) {
    const int mtg = half * 8 + mt;
    float s2v[4];

    #pragma unroll
    for (int s = 0; s < 4; ++s) {
      // ---- s2v at mt top (FIFO position: before this slot's stage) ----
      if (s == 0) {
        #pragma unroll
        for (int c = 0; c < 4; ++c)
          s2v[c] = s2g[mtg * 128 + wc * 64 + c * 16 + l16];
        SB0();
      }
      bf16x8 a2[2];

      // ---- chunk 0: MFMA kc0 | read kc1 + a2 ----
      __builtin_amdgcn_s_setprio(1);
      #pragma unroll
      for (int r = 0; r < 2; ++r)
        #pragma unroll
        for (int c = 0; c < 4; ++c)
          acc_xs[r][c] = __builtin_amdgcn_mfma_f32_16x16x32_fp8_fp8(
              aX[s * 4 + 0][r], bF0[c], acc_xs[r][c], 0, 0, 0);
      __builtin_amdgcn_s_setprio(0);
      SB0();
      rdB(2 * s, 1, bF1);
      if (mt > 0) {
        const int kg = s * 4 + quad;
        #pragma unroll
        for (int r = 0; r < 2; ++r)
          a2[r] = *(const bf16x8*)(smem + 65536 + (kg * 64 + wr * 32 + r * 16 + l16) * 16);
      }
      LGKM0();

      // ---- chunk 1: MFMA kc1 | read kc2 ----
      __builtin_amdgcn_s_setprio(1);
      #pragma unroll
      for (int r = 0; r < 2; ++r)
        #pragma unroll
        for (int c = 0; c < 4; ++c)
          acc_xs[r][c] = __builtin_amdgcn_mfma_f32_16x16x32_fp8_fp8(
              aX[s * 4 + 1][r], bF1[c], acc_xs[r][c], 0, 0, 0);
      __builtin_amdgcn_s_setprio(0);
      SB0();
      rdB(2 * s + 1, 0, bF0);
      LGKM0();

      // ---- chunk 2: MFMA kc2 | read kc3 ----
      __builtin_amdgcn_s_setprio(1);
      #pragma unroll
      for (int r = 0; r < 2; ++r)
        #pragma unroll
        for (int c = 0; c < 4; ++c)
          acc_xs[r][c] = __builtin_amdgcn_mfma_f32_16x16x32_fp8_fp8(
              aX[s * 4 + 2][r], bF0[c], acc_xs[r][c], 0, 0, 0);
      __builtin_amdgcn_s_setprio(0);
      SB0();
      rdB(2 * s + 1, 1, bF1);
      LGKM0();

      // ---- chunk 3: MFMA kc3 | read kc0(T+1) ----
      __builtin_amdgcn_s_setprio(1);
      #pragma unroll
      for (int r = 0; r < 2; ++r)
        #pragma unroll
        for (int c = 0; c < 4; ++c)
          acc_xs[r][c] = __builtin_amdgcn_mfma_f32_16x16x32_fp8_fp8(
              aX[s * 4 + 3][r], bF1[c], acc_xs[r][c], 0, 0, 0);
      __builtin_amdgcn_s_setprio(0);
      SB0();
      if (!(mt == 7 && s == 3)) rdB((2 * s + 2) & 7, 0, bF0);
      LGKM0();

      // ---- gemm2: 4 bf16 MFMA, Ks(mt-1) slab ks=s ----
      if (mt > 0) {
        __builtin_amdgcn_s_setprio(1);
        #pragma unroll
        for (int r = 0; r < 2; ++r)
          #pragma unroll
          for (int c = 0; c < 4; ++c)
            acc_out[r][c] = __builtin_amdgcn_mfma_f32_16x16x32_bf16(
                a2[r], b2[s & 1][c], acc_out[r][c], 0, 0, 0);
        __builtin_amdgcn_s_setprio(0);
      }
      SB0();

      // ---- stage tiles 2T+6, 2T+7 (T <= 28) ----
      if (s == 0 || mt < 7) {
        const int j = mt * 8 + 2 * s + 6;
        stage_tile(j);
        stage_tile(j + 1);
      }
      SB0();

      // ---- b2(T+2) asm loads -> set s&1 (re-using the set consumed above) ----
      if ((s <= 1) ? (mt >= 1) : (mt <= 6)) {
        const int umt = mt + (s >= 2);
        const int us  = (s + 2) & 3;
        const size_t sb = (size_t)((half * 8 + umt - 1) * 16 + us * 4 + quad);
        #pragma unroll
        for (int c = 0; c < 4; ++c)
          b2[s & 1][c] = ldg_b128(hw_ws + (sb * 128 + wc * 64 + c * 16 + l16) * 8);
      }

      // ---- counted wait (drain stage(T-1)+b2(T+1); never 0 in steady) ----
      if (mt == 0)      { if (s == 0) WAITLG(10); else if (s == 1) WAITLG(4); else WAITLG(8); }
      else if (mt < 7)  { if (s == 0) WAITLG(12); else WAITLG(8); }
      else              { if (s == 0) WAITLG(12); else if (s == 1) WAITLG(4); else WAITLG(0); }
      __builtin_amdgcn_s_barrier();
      SB0();
    }

    // ---- epilogue: t = acc + x2g + s2g ; k = min(exp2(-t),1) -> bf16 Ks ----
    {
      #pragma unroll
      for (int r = 0; r < 2; ++r)
        #pragma unroll
        for (int c = 0; c < 4; ++c) {
          const int cl = wc * 64 + c * 16 + l16;     // m-col 0..127
          char* kbase = smem + 65536 + (cl >> 3) * 1024 + (cl & 7) * 2;
          #pragma unroll
          for (int i = 0; i < 4; ++i) {
            const int row = wr * 32 + r * 16 + quad * 4 + i;
            const float t = acc_xs[r][c][i] + x2v[r][i] + s2v[c];
            float kv = __builtin_amdgcn_exp2f(-t);
            kv = fminf(kv, 1.0f);
            *(u16*)(kbase + row * 16) = (u16)(__float_as_uint(kv) >> 16);
            acc_xs[r][c][i] = 0.0f;
          }
        }
    }
    // lgkm-only barrier: Ks writes ordered before next mt's a2 reads; in-flight
    // stages/b2 stay in flight
    LGKM0();
    __builtin_amdgcn_s_barrier();
    SB0();
  }

  // ---- drained GEMM2 for the last mtile ----
  #pragma unroll
  for (int ks = 0; ks < 4; ++ks) {
    const int kg = ks * 4 + quad;
    const size_t sb = (size_t)((half * 8 + 7) * 16 + kg);
    bf16x8 bb[4], a2[2];
    #pragma unroll
    for (int c = 0; c < 4; ++c)
      bb[c] = *(const bf16x8*)(hw_ws + (sb * 128 + wc * 64 + c * 16 + l16) * 8);
    #pragma unroll
    for (int r = 0; r < 2; ++r)
      a2[r] = *(const bf16x8*)(smem + 65536 + (kg * 64 + wr * 32 + r * 16 + l16) * 16);
    #pragma unroll
    for (int r = 0; r < 2; ++r)
      #pragma unroll
      for (int c = 0; c < 4; ++c)
        acc_out[r][c] = __builtin_amdgcn_mfma_f32_16x16x32_bf16(a2[r], bb[c], acc_out[r][c], 0, 0, 0);
  }

  // ---- final: atomic-accumulate scale*acc (+ bias/shift once, by half==0 blocks) ----
  float addv[4];
  #pragma unroll
  for (int c = 0; c < 4; ++c) {
    const int col = wc * 64 + c * 16 + l16;
    addv[c] = (half == 0) ? (vscale * head_b[col] + vshift) : 0.0f;
  }
  #pragma unroll
  for (int r = 0; r < 2; ++r)
    #pragma unroll
    for (int c = 0; c < 4; ++c) {
      const int col = wc * 64 + c * 16 + l16;
      #pragma unroll
      for (int i = 0; i < 4; ++i) {
        const int row = b0 + wr * 32 + r * 16 + quad * 4 + i;
        atomicAdd(&out[(size_t)row * NOUT + col], vscale * acc_out[r][c][i] + addv[c]);
      }
    }
}

// ---------- launch ----------
extern "C" void kernel_launch(void* const* d_in, const int* in_sizes, int n_in,
                              void* d_out, int out_size, void* d_ws, size_t ws_size,
                              hipStream_t stream) {
  const float* x       = (const float*)d_in[0];
  const float* support = (const float*)d_in[1];
  const float* gamma   = (const float*)d_in[2];
  const float* head_w  = (const float*)d_in[3];
  const float* head_b  = (const float*)d_in[4];
  const float* scale   = (const float*)d_in[5];
  const float* shift   = (const float*)d_in[6];
  float* out = (float*)d_out;

  char* w = (char*)d_ws;
  u8*    x_ws  = (u8*)(w);                        //  8,388,608 B
  u8*    s_ws  = (u8*)(w + 8388608);              //  2,097,152 B
  u16*   hw_ws = (u16*)(w + 10485760);            //  1,048,576 B
  float* x2g   = (float*)(w + 11534336);          //     65,536 B
  float* s2g   = (float*)(w + 11599872);          //     16,384 B

  static bool lds_init = false;
  if (!lds_init) {
    hipFuncSetAttribute(reinterpret_cast<const void*>(rbf_fused),
                        hipFuncAttributeMaxDynamicSharedMemorySize, 81920);
    lds_init = true;
  }

  prep_all<<<736, 256, 0, stream>>>(x, support, head_w, gamma,
                                    x_ws, s_ws, hw_ws, x2g, s2g, out);
  rbf_fused<<<1024, 256, 81920, stream>>>(x_ws, s_ws, hw_ws, x2g, s2g,
                                          head_b, scale, shift, out);
}